// Round 12
// baseline (120.753 us; speedup 1.0000x reference)
//
#include <hip/hip_runtime.h>
#include <hip/hip_bf16.h>
#include <math.h>

// Problem constants
#define NB 4
#define NC 4
#define NH 4
#define NN 1024
#define NF 64
#define NCOMBO 64
#define LEAK 0.2f

typedef __attribute__((ext_vector_type(8)))  short  short8;
typedef __attribute__((ext_vector_type(16))) float  float16;

// packed RNE f32x2 -> bf16x2 via v_cvt_pk_bf16_f32 (.x -> low 16, .y -> high 16)
static __device__ __forceinline__ unsigned pk_bf16(float a, float b) {
    union { __hip_bfloat162 h; unsigned u; } cv;
    cv.h = __float22bfloat162_rn(make_float2(a, b));
    return cv.u;
}

// tanh via hardware exp+rcp: 1 - 2/(1+e^{2x}); err ~1e-6, saturates correctly
static __device__ __forceinline__ float fast_tanh(float x) {
    const float e = __expf(2.f * x);
    return 1.f - 2.f * __builtin_amdgcn_rcpf(1.f + e);
}

// async global->LDS, 16B per lane (dst = wave-uniform base + lane*16)
static __device__ __forceinline__ void async_cp16(const void* gsrc, void* ldst) {
    __builtin_amdgcn_global_load_lds(
        (const __attribute__((address_space(1))) unsigned int*)gsrc,
        (__attribute__((address_space(3))) unsigned int*)ldst, 16, 0, 0);
}

// split 8 fp32 -> hi/lo bf16 short8 pair (x = hi + lo, both RNE bf16)
static __device__ __forceinline__ void split8(const float4 a, const float4 b,
                                              short8* hi, short8* lo) {
    union { short8 v; unsigned u[4]; } H, L;
    const float x[8] = {a.x,a.y,a.z,a.w,b.x,b.y,b.z,b.w};
    float lov[8];
    #pragma unroll
    for (int p = 0; p < 4; ++p) {
        const unsigned pk = pk_bf16(x[2*p], x[2*p+1]);
        H.u[p] = pk;
        union { unsigned u; float f; } f0, f1;
        f0.u = pk << 16; f1.u = pk & 0xffff0000u;
        lov[2*p]   = x[2*p]   - f0.f;
        lov[2*p+1] = x[2*p+1] - f1.f;
    }
    #pragma unroll
    for (int p = 0; p < 4; ++p) L.u[p] = pk_bf16(lov[2*p], lov[2*p+1]);
    *hi = H.v; *lo = L.v;
}

// ---------------------------------------------------------------------------
// gA: producer (R9-proven MFMA split-bf16 h@w). Only change vs R9: writes the
// PACKED bf16 exp table tblG[g][j] = (bf16(edN)|bf16(edP)<<16) directly
// (fp32 edP/edN arrays deleted). Scores via butterfly; hp direct to
// frag-order hpt; adj bitmask.
// ---------------------------------------------------------------------------
__global__ __launch_bounds__(256) void gA_produce(
    const float* __restrict__ h, const float* __restrict__ adj,
    const float* __restrict__ w, const float* __restrict__ a_src,
    const float* __restrict__ a_dst,
    unsigned short* __restrict__ hpt, float* __restrict__ asrc,
    unsigned* __restrict__ tblG, unsigned long long* __restrict__ bits)
{
    __shared__ __align__(16) char smem[17920];
    float* w_s    = (float*)smem;
    unsigned short* whi = (unsigned short*)smem;          // 4096 bf16
    unsigned short* wlo = (unsigned short*)(smem + 8192); // 4096 bf16
    float* as_lds = (float*)(smem + 16384);
    float* ad_lds = (float*)(smem + 16640);
    float* scS    = (float*)(smem + 16896);
    float* scD    = (float*)(smem + 17408);

    const int idx  = blockIdx.x;
    const int t    = threadIdx.x;
    const int g    = (idx & 7)*8 + ((idx >> 3) & 7);   // 0..63
    const int tile = idx >> 6;                          // 0..15
    const int b = g >> 4, c = (g >> 2) & 3, hh = g & 3;
    const int lane = t & 63, l31 = lane & 31, half = lane >> 5;
    const int wv = t >> 6, rg = wv >> 1, oh = wv & 1;

    const float4* wsrc = (const float4*)(w + ((size_t)(c*NH + hh))*NF*NF);
    #pragma unroll
    for (int i = 0; i < 4; ++i)
        ((float4*)w_s)[t + i*256] = wsrc[t + i*256];
    if (t < NF) {
        as_lds[t] = a_src[(c*NH + hh)*NF + t];
        ad_lds[t] = a_dst[(c*NH + hh)*NF + t];
    }
    __syncthreads();

    float wv0[8], wv1[8];
    {
        const int n = t & 31;
        #pragma unroll
        for (int j = 0; j < 8; ++j) {
            const int blk0 = t >> 5, blk1 = (t >> 5) + 8;
            const int k0 = (blk0 >> 2)*16 + (blk0 & 1)*8 + j;
            const int o0 = ((blk0 >> 1) & 1)*32 + n;
            const int k1 = (blk1 >> 2)*16 + (blk1 & 1)*8 + j;
            const int o1 = ((blk1 >> 1) & 1)*32 + n;
            wv0[j] = w_s[k0*64 + o0];
            wv1[j] = w_s[k1*64 + o1];
        }
    }
    short8 ahi[4], alo[4];
    {
        const float* hrow = h +
            (((size_t)(b*NC + c))*NN + tile*64 + rg*32 + l31)*NF;
        #pragma unroll
        for (int s = 0; s < 4; ++s) {
            const float4 v0 = *(const float4*)&hrow[s*16 + half*8];
            const float4 v1 = *(const float4*)&hrow[s*16 + half*8 + 4];
            split8(v0, v1, &ahi[s], &alo[s]);
        }
    }
    __syncthreads();

    {
        union { short8 v; unsigned u[4]; } H; short8 L;
        float4 a0 = make_float4(wv0[0],wv0[1],wv0[2],wv0[3]);
        float4 a1 = make_float4(wv0[4],wv0[5],wv0[6],wv0[7]);
        split8(a0, a1, &H.v, &L);
        *(short8*)&whi[((t >> 5)*32 + (t & 31))*8] = H.v;
        *(short8*)&wlo[((t >> 5)*32 + (t & 31))*8] = L;
        a0 = make_float4(wv1[0],wv1[1],wv1[2],wv1[3]);
        a1 = make_float4(wv1[4],wv1[5],wv1[6],wv1[7]);
        split8(a0, a1, &H.v, &L);
        *(short8*)&whi[(((t >> 5) + 8)*32 + (t & 31))*8] = H.v;
        *(short8*)&wlo[(((t >> 5) + 8)*32 + (t & 31))*8] = L;
    }
    __syncthreads();

    float16 acc;
    #pragma unroll
    for (int i = 0; i < 16; ++i) acc[i] = 0.f;
    #pragma unroll
    for (int s = 0; s < 4; ++s) {
        const short8 bhi = *(const short8*)&whi[(((s*2 + oh)*2 + half)*32 + l31)*8];
        const short8 blo = *(const short8*)&wlo[(((s*2 + oh)*2 + half)*32 + l31)*8];
        acc = __builtin_amdgcn_mfma_f32_32x32x16_bf16(ahi[s], bhi, acc, 0, 0, 0);
        acc = __builtin_amdgcn_mfma_f32_32x32x16_bf16(alo[s], bhi, acc, 0, 0, 0);
        acc = __builtin_amdgcn_mfma_f32_32x32x16_bf16(ahi[s], blo, acc, 0, 0, 0);
    }

    {
        const int col = oh*32 + l31;
        const float av = as_lds[col], dv = ad_lds[col];
        float sS[16], sD[16];
        #pragma unroll
        for (int reg = 0; reg < 16; ++reg) {
            const float tt = fast_tanh(acc[reg]);
            sS[reg] = tt * av;
            sD[reg] = tt * dv;
        }
        #pragma unroll
        for (int off = 1; off <= 16; off <<= 1) {
            #pragma unroll
            for (int reg = 0; reg < 16; ++reg) {
                sS[reg] += __shfl_xor(sS[reg], off);
                sD[reg] += __shfl_xor(sD[reg], off);
            }
        }
        if (l31 == 0) {
            #pragma unroll
            for (int reg = 0; reg < 16; ++reg) {
                const int row = rg*32 + (reg & 3) + 8*(reg >> 2) + 4*half;
                scS[row*2 + oh] = sS[reg];
                scD[row*2 + oh] = sD[reg];
            }
        }
    }

    {
        unsigned short* dst = hpt + ((size_t)(g*16 + tile))*4096;
        #pragma unroll
        for (int q = 0; q < 4; ++q) {
            const int ks = rg*2 + (q >> 1), hf = q & 1;
            const int elem = (((ks*2 + oh)*2 + hf)*32 + l31)*8 + 4*half;
            uint2 pk;
            pk.x = pk_bf16(acc[q*4 + 0], acc[q*4 + 1]);
            pk.y = pk_bf16(acc[q*4 + 2], acc[q*4 + 3]);
            *(uint2*)&dst[elem] = pk;
        }
    }
    __syncthreads();
    if (t < 64) {
        const float s = scS[t*2] + scS[t*2 + 1];
        const float d = scD[t*2] + scD[t*2 + 1];
        asrc[(size_t)g*NN + tile*64 + t] = s;
        // packed table: low = bf16(exp(0.2 d)) (edN), high = bf16(exp(d)) (edP)
        tblG[(size_t)g*NN + tile*64 + t] = pk_bf16(__expf(LEAK*d), __expf(d));
    }

    {
        const int base = idx*4096;
        #pragma unroll
        for (int q = 0; q < 16; ++q) {
            const int e  = base + q*256 + t;
            const int j  = e & (NN-1);
            const int i  = (e >> 10) & (NN-1);
            const int bb = e >> 20;
            const bool pred = (adj[e] != 0.f) || (j == i);
            const unsigned long long m = __ballot(pred);
            if ((t & 63) == 0) bits[((size_t)bb*NN + i)*16 + (j >> 6)] = m;
        }
    }
}

// ---------------------------------------------------------------------------
// gC: consumer — R9 structure EXACT (4 blocks/CU, 16 jt, 8KB dbuf tiles,
// ones-MFMA row sums, ratio P-gen) with ONE change: exp tables read from
// GLOBAL tblG (4KB per g, L1-resident — all 4 co-resident blocks share g)
// via dwordx4 on the otherwise-idle VMEM pipe. Halves the LDS-read pipe
// load (the modeled gC bottleneck); tbl LDS buffer + pack prologue deleted.
// ---------------------------------------------------------------------------
__global__ __launch_bounds__(256, 4) void gC_attn(
    const unsigned short* __restrict__ hpt, const float* __restrict__ asrc,
    const unsigned* __restrict__ tblG,
    const unsigned long long* __restrict__ bits, float* __restrict__ out)
{
    // loop:     [0,16384) frag dbuf | [16384,25088) bits_lds | (psum2 unused)
    // epilogue: comb overlays [0,17408) | psum2 [17408,17920)
    __shared__ __align__(16) char smem[25600];
    unsigned short* fragB = (unsigned short*)smem;
    float*          comb  = (float*)smem;
    unsigned long long* bits_lds = (unsigned long long*)(smem + 16384);
    float*          psum2 = (float*)(smem + 17408);

    const int idx = blockIdx.x;
    const int t   = threadIdx.x;
    const int g   = (idx & 7)*8 + ((idx >> 3) & 7);
    const int it  = idx >> 6;
    const int b   = g >> 4;
    const int i0  = it*64;
    const int wv = t >> 6, lane = t & 63;
    const int l31 = lane & 31, half = lane >> 5;
    const int rg = wv >> 1, jh = wv & 1;
    const int myrow = rg*32 + l31;

    // DMA tile 0 into buffer 0
    {
        const char* gs = (const char*)hpt + ((size_t)g*16)*8192 + wv*2048 + lane*16;
        char* ls = smem + wv*2048;
        async_cp16(gs, ls);
        async_cp16(gs + 1024, ls + 1024);
    }
    // mask bits
    {
        const unsigned long long* bsrc = bits + ((size_t)b*NN + i0)*16;
        #pragma unroll
        for (int q = 0; q < 4; ++q) {
            const int e = q*256 + t;
            bits_lds[(e >> 4)*17 + (e & 15)] = bsrc[e];
        }
    }
    const float sv    = asrc[(size_t)g*NN + i0 + myrow];
    const float ratio = __expf((LEAK - 1.f)*sv);
    const unsigned* tb = tblG + (size_t)g*NN;

    union { short8 v; unsigned short u[8]; } ONES;
    #pragma unroll
    for (int i = 0; i < 8; ++i) ONES.u[i] = 0x3F80;

    float16 acc0, acc1, acc2;
    #pragma unroll
    for (int i = 0; i < 16; ++i) { acc0[i] = 0.f; acc1[i] = 0.f; acc2[i] = 0.f; }

    for (int jt = 0; jt < 16; ++jt) {
        __syncthreads();   // tile jt's DMA landed; other-buffer reads done
        const int fb = jt & 1;
        if (jt < 15) {
            const char* gs = (const char*)hpt + ((size_t)g*16 + jt + 1)*8192
                             + wv*2048 + lane*16;
            char* ls = smem + ((jt + 1) & 1)*8192 + wv*2048;
            async_cp16(gs, ls);
            async_cp16(gs + 1024, ls + 1024);
        }
        const unsigned long long wb = bits_lds[myrow*17 + jt];

        #pragma unroll
        for (int kk = 0; kk < 2; ++kk) {
            const int ks = jh*2 + kk;
            const int jo = ks*16 + half*8;
            const uint4 Ta = *(const uint4*)&tb[jt*64 + jo];      // global, L1-hot
            const uint4 Tb = *(const uint4*)&tb[jt*64 + jo + 4];  // global, L1-hot
            const short8 b0 = *(const short8*)
                &fragB[fb*4096 + (((ks*2 + 0)*2 + half)*32 + l31)*8];
            const short8 b1 = *(const short8*)
                &fragB[fb*4096 + (((ks*2 + 1)*2 + half)*32 + l31)*8];
            const unsigned bb = (unsigned)(wb >> jo) & 0xffu;

            float p0, p1, p2, p3, p4, p5, p6, p7;
            {
                union { unsigned u; float f; } hi, lo;
                hi.u = Ta.x & 0xffff0000u; lo.u = Ta.x << 16;
                p0 = fmaxf(hi.f, ratio*lo.f); p0 = (bb & 1u)   ? p0 : 0.f;
                hi.u = Ta.y & 0xffff0000u; lo.u = Ta.y << 16;
                p1 = fmaxf(hi.f, ratio*lo.f); p1 = (bb & 2u)   ? p1 : 0.f;
                hi.u = Ta.z & 0xffff0000u; lo.u = Ta.z << 16;
                p2 = fmaxf(hi.f, ratio*lo.f); p2 = (bb & 4u)   ? p2 : 0.f;
                hi.u = Ta.w & 0xffff0000u; lo.u = Ta.w << 16;
                p3 = fmaxf(hi.f, ratio*lo.f); p3 = (bb & 8u)   ? p3 : 0.f;
                hi.u = Tb.x & 0xffff0000u; lo.u = Tb.x << 16;
                p4 = fmaxf(hi.f, ratio*lo.f); p4 = (bb & 16u)  ? p4 : 0.f;
                hi.u = Tb.y & 0xffff0000u; lo.u = Tb.y << 16;
                p5 = fmaxf(hi.f, ratio*lo.f); p5 = (bb & 32u)  ? p5 : 0.f;
                hi.u = Tb.z & 0xffff0000u; lo.u = Tb.z << 16;
                p6 = fmaxf(hi.f, ratio*lo.f); p6 = (bb & 64u)  ? p6 : 0.f;
                hi.u = Tb.w & 0xffff0000u; lo.u = Tb.w << 16;
                p7 = fmaxf(hi.f, ratio*lo.f); p7 = (bb & 128u) ? p7 : 0.f;
            }

            union { short8 v; unsigned u[4]; } af;
            af.u[0] = pk_bf16(p0, p1);
            af.u[1] = pk_bf16(p2, p3);
            af.u[2] = pk_bf16(p4, p5);
            af.u[3] = pk_bf16(p6, p7);

            acc2 = __builtin_amdgcn_mfma_f32_32x32x16_bf16(af.v, ONES.v, acc2, 0, 0, 0);
            acc0 = __builtin_amdgcn_mfma_f32_32x32x16_bf16(af.v, b0,     acc0, 0, 0, 0);
            acc1 = __builtin_amdgcn_mfma_f32_32x32x16_bf16(af.v, b1,     acc1, 0, 0, 0);
        }
    }

    __syncthreads();   // loop reads done -> overlay comb; bits dead -> psum2 ok

    if (l31 == 0) {
        #pragma unroll
        for (int reg = 0; reg < 16; ++reg) {
            const int r = (reg & 3) + 8*(reg >> 2) + 4*half;
            psum2[jh*64 + rg*32 + r] = acc2[reg];
        }
    }
    if (jh == 1) {
        float* cb = comb + (rg*64 + lane)*34;
        #pragma unroll
        for (int i = 0; i < 8; ++i) {
            float2 v0; v0.x = acc0[2*i]; v0.y = acc0[2*i+1];
            float2 v1; v1.x = acc1[2*i]; v1.y = acc1[2*i+1];
            *(float2*)&cb[2*i]      = v0;
            *(float2*)&cb[16 + 2*i] = v1;
        }
    }
    __syncthreads();
    if (jh == 0) {
        const float* cb = comb + (rg*64 + lane)*34;
        #pragma unroll
        for (int i = 0; i < 8; ++i) {
            const float2 v0 = *(const float2*)&cb[2*i];
            const float2 v1 = *(const float2*)&cb[16 + 2*i];
            acc0[2*i] += v0.x; acc0[2*i+1] += v0.y;
            acc1[2*i] += v1.x; acc1[2*i+1] += v1.y;
        }
        #pragma unroll
        for (int reg = 0; reg < 16; ++reg) {
            const int r = (reg & 3) + 8*(reg >> 2) + 4*half;
            const int row = rg*32 + r;
            const float inv = __builtin_amdgcn_rcpf(psum2[row] + psum2[64 + row]);
            const size_t base = ((size_t)g*NN + i0 + row)*NF;
            out[base + l31]      = acc0[reg] * inv;
            out[base + l31 + 32] = acc1[reg] * inv;
        }
    }
}

// ---------------------------------------------------------------------------
extern "C" void kernel_launch(void* const* d_in, const int* in_sizes, int n_in,
                              void* d_out, int out_size, void* d_ws, size_t ws_size,
                              hipStream_t stream)
{
    const float* h     = (const float*)d_in[0];
    const float* adj   = (const float*)d_in[1];
    const float* w     = (const float*)d_in[2];
    const float* a_src = (const float*)d_in[3];
    const float* a_dst = (const float*)d_in[4];
    float* out = (float*)d_out;

    char* ws = (char*)d_ws;
    // ws: hpt bf16 [64][16][4096] frag-order (8,388,608) | asrc (262,144)
    //     | tblG u32 [64][1024] (262,144) | bits u64 [4][1024][16] (524,288)
    unsigned short* hpt = (unsigned short*)ws;
    float* asrc         = (float*)(ws + 8388608);
    unsigned* tblG      = (unsigned*)(ws + 8388608 + 262144);
    unsigned long long* bits = (unsigned long long*)(ws + 8388608 + 524288);

    gA_produce<<<dim3(1024), dim3(256), 0, stream>>>(
        h, adj, w, a_src, a_dst, hpt, asrc, tblG, bits);
    gC_attn<<<dim3(1024), dim3(256), 0, stream>>>(
        hpt, asrc, tblG, bits, out);
}

// Round 14
// 119.494 us; speedup vs baseline: 1.0105x; 1.0105x over previous
//
#include <hip/hip_runtime.h>
#include <hip/hip_bf16.h>
#include <math.h>

// Problem constants
#define NB 4
#define NC 4
#define NH 4
#define NN 1024
#define NF 64
#define NCOMBO 64
#define LEAK 0.2f

typedef __attribute__((ext_vector_type(8)))  short  short8;
typedef __attribute__((ext_vector_type(16))) float  float16;

// packed RNE f32x2 -> bf16x2 via v_cvt_pk_bf16_f32 (.x -> low 16, .y -> high 16)
static __device__ __forceinline__ unsigned pk_bf16(float a, float b) {
    union { __hip_bfloat162 h; unsigned u; } cv;
    cv.h = __float22bfloat162_rn(make_float2(a, b));
    return cv.u;
}

// tanh via hardware exp+rcp: 1 - 2/(1+e^{2x}); err ~1e-6, saturates correctly
static __device__ __forceinline__ float fast_tanh(float x) {
    const float e = __expf(2.f * x);
    return 1.f - 2.f * __builtin_amdgcn_rcpf(1.f + e);
}

// async global->LDS, 16B per lane (LDS dst = wave-uniform base + lane*16)
static __device__ __forceinline__ void async_cp16(const void* gsrc, void* ldst) {
    __builtin_amdgcn_global_load_lds(
        (const __attribute__((address_space(1))) unsigned int*)gsrc,
        (__attribute__((address_space(3))) unsigned int*)ldst, 16, 0, 0);
}

// manual waits; memory clobber pins ordering of surrounding memory ops
static __device__ __forceinline__ void wait_vm4()  { asm volatile("s_waitcnt vmcnt(4)"   ::: "memory"); }
static __device__ __forceinline__ void wait_vm2()  { asm volatile("s_waitcnt vmcnt(2)"   ::: "memory"); }
static __device__ __forceinline__ void wait_vm0()  { asm volatile("s_waitcnt vmcnt(0)"   ::: "memory"); }
static __device__ __forceinline__ void wait_lgkm0(){ asm volatile("s_waitcnt lgkmcnt(0)" ::: "memory"); }
static __device__ __forceinline__ void wait_vm(int s) {
    if (s < 30) wait_vm4(); else if (s == 30) wait_vm2(); else wait_vm0();
}

// split 8 fp32 -> hi/lo bf16 short8 pair (x = hi + lo, both RNE bf16)
static __device__ __forceinline__ void split8(const float4 a, const float4 b,
                                              short8* hi, short8* lo) {
    union { short8 v; unsigned u[4]; } H, L;
    const float x[8] = {a.x,a.y,a.z,a.w,b.x,b.y,b.z,b.w};
    float lov[8];
    #pragma unroll
    for (int p = 0; p < 4; ++p) {
        const unsigned pk = pk_bf16(x[2*p], x[2*p+1]);
        H.u[p] = pk;
        union { unsigned u; float f; } f0, f1;
        f0.u = pk << 16; f1.u = pk & 0xffff0000u;
        lov[2*p]   = x[2*p]   - f0.f;
        lov[2*p+1] = x[2*p+1] - f1.f;
    }
    #pragma unroll
    for (int p = 0; p < 4; ++p) L.u[p] = pk_bf16(lov[2*p], lov[2*p+1]);
    *hi = H.v; *lo = L.v;
}

// ---------------------------------------------------------------------------
// gA: producer (UNCHANGED from R11). MFMA split-bf16 h@w; scores via
// butterfly; hp direct to frag-order hpt; packed exp table tblG; adj bitmask.
// ---------------------------------------------------------------------------
__global__ __launch_bounds__(256) void gA_produce(
    const float* __restrict__ h, const float* __restrict__ adj,
    const float* __restrict__ w, const float* __restrict__ a_src,
    const float* __restrict__ a_dst,
    unsigned short* __restrict__ hpt, float* __restrict__ asrc,
    unsigned* __restrict__ tblG, unsigned long long* __restrict__ bits)
{
    __shared__ __align__(16) char smem[17920];
    float* w_s    = (float*)smem;
    unsigned short* whi = (unsigned short*)smem;          // 4096 bf16
    unsigned short* wlo = (unsigned short*)(smem + 8192); // 4096 bf16
    float* as_lds = (float*)(smem + 16384);
    float* ad_lds = (float*)(smem + 16640);
    float* scS    = (float*)(smem + 16896);
    float* scD    = (float*)(smem + 17408);

    const int idx  = blockIdx.x;
    const int t    = threadIdx.x;
    const int g    = (idx & 7)*8 + ((idx >> 3) & 7);   // 0..63
    const int tile = idx >> 6;                          // 0..15
    const int b = g >> 4, c = (g >> 2) & 3, hh = g & 3;
    const int lane = t & 63, l31 = lane & 31, half = lane >> 5;
    const int wv = t >> 6, rg = wv >> 1, oh = wv & 1;

    const float4* wsrc = (const float4*)(w + ((size_t)(c*NH + hh))*NF*NF);
    #pragma unroll
    for (int i = 0; i < 4; ++i)
        ((float4*)w_s)[t + i*256] = wsrc[t + i*256];
    if (t < NF) {
        as_lds[t] = a_src[(c*NH + hh)*NF + t];
        ad_lds[t] = a_dst[(c*NH + hh)*NF + t];
    }
    __syncthreads();

    float wv0[8], wv1[8];
    {
        const int n = t & 31;
        #pragma unroll
        for (int j = 0; j < 8; ++j) {
            const int blk0 = t >> 5, blk1 = (t >> 5) + 8;
            const int k0 = (blk0 >> 2)*16 + (blk0 & 1)*8 + j;
            const int o0 = ((blk0 >> 1) & 1)*32 + n;
            const int k1 = (blk1 >> 2)*16 + (blk1 & 1)*8 + j;
            const int o1 = ((blk1 >> 1) & 1)*32 + n;
            wv0[j] = w_s[k0*64 + o0];
            wv1[j] = w_s[k1*64 + o1];
        }
    }
    short8 ahi[4], alo[4];
    {
        const float* hrow = h +
            (((size_t)(b*NC + c))*NN + tile*64 + rg*32 + l31)*NF;
        #pragma unroll
        for (int s = 0; s < 4; ++s) {
            const float4 v0 = *(const float4*)&hrow[s*16 + half*8];
            const float4 v1 = *(const float4*)&hrow[s*16 + half*8 + 4];
            split8(v0, v1, &ahi[s], &alo[s]);
        }
    }
    __syncthreads();

    {
        union { short8 v; unsigned u[4]; } H; short8 L;
        float4 a0 = make_float4(wv0[0],wv0[1],wv0[2],wv0[3]);
        float4 a1 = make_float4(wv0[4],wv0[5],wv0[6],wv0[7]);
        split8(a0, a1, &H.v, &L);
        *(short8*)&whi[((t >> 5)*32 + (t & 31))*8] = H.v;
        *(short8*)&wlo[((t >> 5)*32 + (t & 31))*8] = L;
        a0 = make_float4(wv1[0],wv1[1],wv1[2],wv1[3]);
        a1 = make_float4(wv1[4],wv1[5],wv1[6],wv1[7]);
        split8(a0, a1, &H.v, &L);
        *(short8*)&whi[(((t >> 5) + 8)*32 + (t & 31))*8] = H.v;
        *(short8*)&wlo[(((t >> 5) + 8)*32 + (t & 31))*8] = L;
    }
    __syncthreads();

    float16 acc;
    #pragma unroll
    for (int i = 0; i < 16; ++i) acc[i] = 0.f;
    #pragma unroll
    for (int s = 0; s < 4; ++s) {
        const short8 bhi = *(const short8*)&whi[(((s*2 + oh)*2 + half)*32 + l31)*8];
        const short8 blo = *(const short8*)&wlo[(((s*2 + oh)*2 + half)*32 + l31)*8];
        acc = __builtin_amdgcn_mfma_f32_32x32x16_bf16(ahi[s], bhi, acc, 0, 0, 0);
        acc = __builtin_amdgcn_mfma_f32_32x32x16_bf16(alo[s], bhi, acc, 0, 0, 0);
        acc = __builtin_amdgcn_mfma_f32_32x32x16_bf16(ahi[s], blo, acc, 0, 0, 0);
    }

    {
        const int col = oh*32 + l31;
        const float av = as_lds[col], dv = ad_lds[col];
        float sS[16], sD[16];
        #pragma unroll
        for (int reg = 0; reg < 16; ++reg) {
            const float tt = fast_tanh(acc[reg]);
            sS[reg] = tt * av;
            sD[reg] = tt * dv;
        }
        #pragma unroll
        for (int off = 1; off <= 16; off <<= 1) {
            #pragma unroll
            for (int reg = 0; reg < 16; ++reg) {
                sS[reg] += __shfl_xor(sS[reg], off);
                sD[reg] += __shfl_xor(sD[reg], off);
            }
        }
        if (l31 == 0) {
            #pragma unroll
            for (int reg = 0; reg < 16; ++reg) {
                const int row = rg*32 + (reg & 3) + 8*(reg >> 2) + 4*half;
                scS[row*2 + oh] = sS[reg];
                scD[row*2 + oh] = sD[reg];
            }
        }
    }

    {
        unsigned short* dst = hpt + ((size_t)(g*16 + tile))*4096;
        #pragma unroll
        for (int q = 0; q < 4; ++q) {
            const int ks = rg*2 + (q >> 1), hf = q & 1;
            const int elem = (((ks*2 + oh)*2 + hf)*32 + l31)*8 + 4*half;
            uint2 pk;
            pk.x = pk_bf16(acc[q*4 + 0], acc[q*4 + 1]);
            pk.y = pk_bf16(acc[q*4 + 2], acc[q*4 + 3]);
            *(uint2*)&dst[elem] = pk;
        }
    }
    __syncthreads();
    if (t < 64) {
        const float s = scS[t*2] + scS[t*2 + 1];
        const float d = scD[t*2] + scD[t*2 + 1];
        asrc[(size_t)g*NN + tile*64 + t] = s;
        tblG[(size_t)g*NN + tile*64 + t] = pk_bf16(__expf(LEAK*d), __expf(d));
    }

    {
        const int base = idx*4096;
        #pragma unroll
        for (int q = 0; q < 16; ++q) {
            const int e  = base + q*256 + t;
            const int j  = e & (NN-1);
            const int i  = (e >> 10) & (NN-1);
            const int bb = e >> 20;
            const bool pred = (adj[e] != 0.f) || (j == i);
            const unsigned long long m = __ballot(pred);
            if ((t & 63) == 0) bits[((size_t)bb*NN + i)*16 + (j >> 6)] = m;
        }
    }
}

// ---------------------------------------------------------------------------
// gC v5: barrier-free K-loop (R12) + WAR-race fix. Per-wave 3x2KB LDS ring,
// self-paced DMA, prefetch distance 2.
//   RAW: wait vmcnt(4) retires stage s before its buffer is read
//        (prologue __syncthreads zeroes the vmcnt baseline).
//   WAR: s_waitcnt lgkmcnt(0) BEFORE each prefetch issue drains the previous
//        iteration's ds_reads — the last readers of the buffer stage s+2
//        overwrites — so the DMA can never land under a queued read.
// Tables + mask bits in LDS; ones-MFMA row sums; ratio-form P-gen.
// LDS 36.5KB -> 4 blocks/CU.
// ---------------------------------------------------------------------------
__global__ __launch_bounds__(256, 4) void gC_attn(
    const unsigned short* __restrict__ hpt, const float* __restrict__ asrc,
    const unsigned* __restrict__ tblG,
    const unsigned long long* __restrict__ bits, float* __restrict__ out)
{
    // [0,24576): per-wave rings (wave wv at wv*6144, 3 buffers x 2048B)
    // [24576,28672): packed tbl (1024 u32)
    // [28672,37376): bits_lds (64*17 u64)
    // epilogue overlays: comb on [0,17408) | psum2 on [28672,29184)
    __shared__ __align__(16) char smem[37376];
    unsigned*       tbl   = (unsigned*)(smem + 24576);
    unsigned long long* bits_lds = (unsigned long long*)(smem + 28672);
    float*          comb  = (float*)smem;
    float*          psum2 = (float*)(smem + 28672);

    const int idx = blockIdx.x;
    const int t   = threadIdx.x;
    const int g   = (idx & 7)*8 + ((idx >> 3) & 7);
    const int it  = idx >> 6;
    const int b   = g >> 4;
    const int i0  = it*64;
    const int wv = t >> 6, lane = t & 63;
    const int l31 = lane & 31, half = lane >> 5;
    const int rg = wv >> 1, jh = wv & 1;
    const int myrow = rg*32 + l31;

    const char* hbase = (const char*)hpt + ((size_t)g*16)*8192 + jh*4096 + lane*16;
    char* ring = smem + wv*6144;

    // issue stages 0,1 (tile 0, kk 0/1) into ring buffers 0,1
    async_cp16(hbase,        ring);
    async_cp16(hbase + 1024, ring + 1024);
    async_cp16(hbase + 2048, ring + 2048);
    async_cp16(hbase + 3072, ring + 3072);

    // prologue: packed tables + mask bits + per-row ratio
    #pragma unroll
    for (int q = 0; q < 4; ++q) {
        const int j = q*256 + t;
        tbl[j] = tblG[(size_t)g*NN + j];
    }
    {
        const unsigned long long* bsrc = bits + ((size_t)b*NN + i0)*16;
        #pragma unroll
        for (int q = 0; q < 4; ++q) {
            const int e = q*256 + t;
            bits_lds[(e >> 4)*17 + (e & 15)] = bsrc[e];
        }
    }
    const float sv    = asrc[(size_t)g*NN + i0 + myrow];
    const float ratio = __expf((LEAK - 1.f)*sv);

    union { short8 v; unsigned short u[8]; } ONES;
    #pragma unroll
    for (int i = 0; i < 8; ++i) ONES.u[i] = 0x3F80;

    float16 acc0, acc1, acc2;
    #pragma unroll
    for (int i = 0; i < 16; ++i) { acc0[i] = 0.f; acc1[i] = 0.f; acc2[i] = 0.f; }

    __syncthreads();   // tbl + bits visible; drains vm+lgkm (counter baseline 0)

    #pragma unroll
    for (int jt = 0; jt < 16; ++jt) {
        const unsigned long long wb = bits_lds[myrow*17 + jt];

        #pragma unroll
        for (int kk = 0; kk < 2; ++kk) {
            const int s = jt*2 + kk;
            if (s < 30) {   // issue stage s+2 into ring buffer (s+2)%3
                wait_lgkm0();   // WAR fix: prior iter's ds_reads retired before overwrite
                const int t2 = s + 2;
                const char* gs = hbase + (size_t)(t2 >> 1)*8192 + (t2 & 1)*2048;
                char* ls = ring + (t2 % 3)*2048;
                async_cp16(gs, ls);
                async_cp16(gs + 1024, ls + 1024);
            }
            wait_vm(s);     // stage s's 2 loads landed (oldest outstanding)

            const int ks = jh*2 + kk;
            const int jo = ks*16 + half*8;
            const uint4 Ta = *(const uint4*)&tbl[jt*64 + jo];
            const uint4 Tb = *(const uint4*)&tbl[jt*64 + jo + 4];
            const char* sb = ring + (s % 3)*2048;
            const short8 b0 = *(const short8*)(sb + half*512 + l31*16);
            const short8 b1 = *(const short8*)(sb + 1024 + half*512 + l31*16);
            const unsigned bb = (unsigned)(wb >> jo) & 0xffu;

            float p0, p1, p2, p3, p4, p5, p6, p7;
            {
                union { unsigned u; float f; } hi, lo;
                hi.u = Ta.x & 0xffff0000u; lo.u = Ta.x << 16;
                p0 = fmaxf(hi.f, ratio*lo.f); p0 = (bb & 1u)   ? p0 : 0.f;
                hi.u = Ta.y & 0xffff0000u; lo.u = Ta.y << 16;
                p1 = fmaxf(hi.f, ratio*lo.f); p1 = (bb & 2u)   ? p1 : 0.f;
                hi.u = Ta.z & 0xffff0000u; lo.u = Ta.z << 16;
                p2 = fmaxf(hi.f, ratio*lo.f); p2 = (bb & 4u)   ? p2 : 0.f;
                hi.u = Ta.w & 0xffff0000u; lo.u = Ta.w << 16;
                p3 = fmaxf(hi.f, ratio*lo.f); p3 = (bb & 8u)   ? p3 : 0.f;
                hi.u = Tb.x & 0xffff0000u; lo.u = Tb.x << 16;
                p4 = fmaxf(hi.f, ratio*lo.f); p4 = (bb & 16u)  ? p4 : 0.f;
                hi.u = Tb.y & 0xffff0000u; lo.u = Tb.y << 16;
                p5 = fmaxf(hi.f, ratio*lo.f); p5 = (bb & 32u)  ? p5 : 0.f;
                hi.u = Tb.z & 0xffff0000u; lo.u = Tb.z << 16;
                p6 = fmaxf(hi.f, ratio*lo.f); p6 = (bb & 64u)  ? p6 : 0.f;
                hi.u = Tb.w & 0xffff0000u; lo.u = Tb.w << 16;
                p7 = fmaxf(hi.f, ratio*lo.f); p7 = (bb & 128u) ? p7 : 0.f;
            }

            union { short8 v; unsigned u[4]; } af;
            af.u[0] = pk_bf16(p0, p1);
            af.u[1] = pk_bf16(p2, p3);
            af.u[2] = pk_bf16(p4, p5);
            af.u[3] = pk_bf16(p6, p7);

            acc2 = __builtin_amdgcn_mfma_f32_32x32x16_bf16(af.v, ONES.v, acc2, 0, 0, 0);
            acc0 = __builtin_amdgcn_mfma_f32_32x32x16_bf16(af.v, b0,     acc0, 0, 0, 0);
            acc1 = __builtin_amdgcn_mfma_f32_32x32x16_bf16(af.v, b1,     acc1, 0, 0, 0);
        }
    }

    __syncthreads();   // all waves done -> overlay comb/psum2

    if (l31 == 0) {
        #pragma unroll
        for (int reg = 0; reg < 16; ++reg) {
            const int r = (reg & 3) + 8*(reg >> 2) + 4*half;
            psum2[jh*64 + rg*32 + r] = acc2[reg];
        }
    }
    if (jh == 1) {
        float* cb = comb + (rg*64 + lane)*34;
        #pragma unroll
        for (int i = 0; i < 8; ++i) {
            float2 v0; v0.x = acc0[2*i]; v0.y = acc0[2*i+1];
            float2 v1; v1.x = acc1[2*i]; v1.y = acc1[2*i+1];
            *(float2*)&cb[2*i]      = v0;
            *(float2*)&cb[16 + 2*i] = v1;
        }
    }
    __syncthreads();
    if (jh == 0) {
        const float* cb = comb + (rg*64 + lane)*34;
        #pragma unroll
        for (int i = 0; i < 8; ++i) {
            const float2 v0 = *(const float2*)&cb[2*i];
            const float2 v1 = *(const float2*)&cb[16 + 2*i];
            acc0[2*i] += v0.x; acc0[2*i+1] += v0.y;
            acc1[2*i] += v1.x; acc1[2*i+1] += v1.y;
        }
        #pragma unroll
        for (int reg = 0; reg < 16; ++reg) {
            const int r = (reg & 3) + 8*(reg >> 2) + 4*half;
            const int row = rg*32 + r;
            const float inv = __builtin_amdgcn_rcpf(psum2[row] + psum2[64 + row]);
            const size_t base = ((size_t)g*NN + i0 + row)*NF;
            out[base + l31]      = acc0[reg] * inv;
            out[base + l31 + 32] = acc1[reg] * inv;
        }
    }
}

// ---------------------------------------------------------------------------
extern "C" void kernel_launch(void* const* d_in, const int* in_sizes, int n_in,
                              void* d_out, int out_size, void* d_ws, size_t ws_size,
                              hipStream_t stream)
{
    const float* h     = (const float*)d_in[0];
    const float* adj   = (const float*)d_in[1];
    const float* w     = (const float*)d_in[2];
    const float* a_src = (const float*)d_in[3];
    const float* a_dst = (const float*)d_in[4];
    float* out = (float*)d_out;

    char* ws = (char*)d_ws;
    // ws: hpt bf16 [64][16][4096] frag-order (8,388,608) | asrc (262,144)
    //     | tblG u32 [64][1024] (262,144) | bits u64 [4][1024][16] (524,288)
    unsigned short* hpt = (unsigned short*)ws;
    float* asrc         = (float*)(ws + 8388608);
    unsigned* tblG      = (unsigned*)(ws + 8388608 + 262144);
    unsigned long long* bits = (unsigned long long*)(ws + 8388608 + 524288);

    gA_produce<<<dim3(1024), dim3(256), 0, stream>>>(
        h, adj, w, a_src, a_dst, hpt, asrc, tblG, bits);
    gC_attn<<<dim3(1024), dim3(256), 0, stream>>>(
        hpt, asrc, tblG, bits, out);
}